// Round 3
// baseline (160.543 us; speedup 1.0000x reference)
//
#include <hip/hip_runtime.h>

#define NSAMP 64
#define ELEMS (512 * 512)       // per-sample elements = 262144
#define NBLK  64                // blocks per sample
#define GRID  (NSAMP * NBLK)    // 4096 blocks
#define TPB   256
#define PB    (ELEMS / NBLK)    // 4096 elements per block
#define N4    (PB / 4)          // 1024 float4 per block
#define UNR   (N4 / TPB)        // 4 float4 per thread per array

// ws layout (floats):
//   [0 .. GRID*4)             per-block partials, one float4 per block (64 KiB)
//   bytes [65536 .. 65536+4096)   64 per-sample counters, 64B stride
//   bytes [69632 .. 69636)        global counter
#define CNT_BYTE_OFF   65536
#define GCNT_BYTE_OFF  (CNT_BYTE_OFF + 64 * 64)
#define CNT_CLEAR_SZ   (64 * 64 + 64)

__device__ __forceinline__ float sigmoid_fast(float x) {
    float e = __expf(-x);
    return __builtin_amdgcn_rcpf(1.0f + e);   // 1 ulp rcp, fine at 2e-2 tolerance
}

__global__ __launch_bounds__(TPB) void fused_kernel(
    const float* __restrict__ seg, const float* __restrict__ msk,
    const float* __restrict__ pc, const int* __restrict__ labels,
    float* __restrict__ ws, float* __restrict__ out)
{
    const int bid = blockIdx.x;
    const int b   = bid >> 6;                 // sample
    const int blk = bid & (NBLK - 1);         // chunk within sample
    const size_t base = (size_t)b * ELEMS + (size_t)blk * PB;
    const float4* s4 = (const float4*)(seg + base);
    const float4* m4 = (const float4*)(msk + base);

    float4 xs[UNR], ms[UNR];
    #pragma unroll
    for (int u = 0; u < UNR; ++u) xs[u] = s4[threadIdx.x + u * TPB];
    #pragma unroll
    for (int u = 0; u < UNR; ++u) ms[u] = m4[threadIdx.x + u * TPB];

    float pg = 0.f, pp = 0.f, gg = 0.f, sm = 0.f;
    #pragma unroll
    for (int u = 0; u < UNR; ++u) {
        float4 x = xs[u], m = ms[u];
        float s0 = sigmoid_fast(x.x);
        float s1 = sigmoid_fast(x.y);
        float s2 = sigmoid_fast(x.z);
        float s3 = sigmoid_fast(x.w);
        pg = fmaf(s0, m.x, pg); pg = fmaf(s1, m.y, pg);
        pg = fmaf(s2, m.z, pg); pg = fmaf(s3, m.w, pg);
        pp = fmaf(s0, s0, pp);  pp = fmaf(s1, s1, pp);
        pp = fmaf(s2, s2, pp);  pp = fmaf(s3, s3, pp);
        gg += (m.x + m.y) + (m.z + m.w);      // masks are 0/1 -> m*m == m
        sm += (s0 + s1) + (s2 + s3);
    }

    // wave reduce
    #pragma unroll
    for (int o = 32; o; o >>= 1) {
        pg += __shfl_down(pg, o);
        pp += __shfl_down(pp, o);
        gg += __shfl_down(gg, o);
        sm += __shfl_down(sm, o);
    }

    // cross-wave reduce (4 waves)
    __shared__ float red[TPB / 64][4];
    __shared__ int   flag;
    const int lane = threadIdx.x & 63;
    const int wid  = threadIdx.x >> 6;
    if (lane == 0) {
        red[wid][0] = pg; red[wid][1] = pp;
        red[wid][2] = gg; red[wid][3] = sm;
    }
    __syncthreads();

    unsigned* cnts = (unsigned*)((char*)ws + CNT_BYTE_OFF);   // stride 16 uints
    unsigned* gcnt = (unsigned*)((char*)ws + GCNT_BYTE_OFF);

    if (threadIdx.x == 0) {
        float a = red[0][0] + red[1][0] + red[2][0] + red[3][0];
        float c = red[0][1] + red[1][1] + red[2][1] + red[3][1];
        float d = red[0][2] + red[1][2] + red[2][2] + red[3][2];
        float e = red[0][3] + red[1][3] + red[2][3] + red[3][3];
        ((float4*)ws)[bid] = make_float4(a, c, d, e);
        __threadfence();                       // release: partial visible device-wide
        int done = 0;
        unsigned o1 = atomicAdd(&cnts[(size_t)b * 16], 1u);
        if (o1 == NBLK - 1) {                  // last block of this sample
            unsigned o2 = atomicAdd(gcnt, 1u);
            done = (o2 == NSAMP - 1);          // last sample to complete
        }
        flag = done;
    }
    __syncthreads();
    if (!flag) return;

    // ---- finalize (exactly one block reaches here) ----
    __threadfence();                           // acquire: see all partials
    const int t = threadIdx.x;
    const int bb = t & 63;
    const int q  = t >> 6;
    const float4* w4 = (const float4*)ws;

    float4 acc = make_float4(0.f, 0.f, 0.f, 0.f);
    #pragma unroll
    for (int i = 0; i < NBLK / 4; ++i) {       // 16 float4 per (bb,q)
        float4 v = w4[(size_t)bb * NBLK + q * (NBLK / 4) + i];
        acc.x += v.x; acc.y += v.y; acc.z += v.z; acc.w += v.w;
    }

    __shared__ float4 red2[TPB];
    red2[t] = acc;
    __syncthreads();

    if (t < 64) {
        float4 a0 = red2[t], a1 = red2[t + 64], a2 = red2[t + 128], a3 = red2[t + 192];
        float spg = (a0.x + a1.x) + (a2.x + a3.x);
        float spp = (a0.y + a1.y) + (a2.y + a3.y);
        float sgg = (a0.z + a1.z) + (a2.z + a3.z);
        float ssm = (a0.w + a1.w) + (a2.w + a3.w);

        float p   = pc[bb];
        float lab = (float)labels[bb];

        const float eps = 1e-7f;
        float pcc = fminf(fmaxf(p, eps), 1.f - eps);
        float bce = -(lab * logf(pcc) + (1.f - lab) * logf(1.f - pcc));

        float dice_pos = (2.f * spg + 1e-5f) / (spp + sgg + 1e-5f);
        float dice_neg = 25.f / (ssm + 25.f);
        float dice = (lab == 1.f) ? dice_pos : dice_neg;

        float sel  = (p >= 0.5f) ? 1.f : 0.f;
        float nsel = sel;
        float dsum = sel * dice;

        #pragma unroll
        for (int o = 32; o; o >>= 1) {
            bce  += __shfl_down(bce, o);
            nsel += __shfl_down(nsel, o);
            dsum += __shfl_down(dsum, o);
        }

        if (bb == 0) {
            out[0] = bce * (1.0f / 64.0f);
            out[1] = (nsel > 0.f) ? (nsel - dsum) / fmaxf(nsel, 1.f) : 1e-4f;
        }
    }
}

extern "C" void kernel_launch(void* const* d_in, const int* in_sizes, int n_in,
                              void* d_out, int out_size, void* d_ws, size_t ws_size,
                              hipStream_t stream) {
    const float* predict_cls = (const float*)d_in[0];   // [64]
    const float* predict_seg = (const float*)d_in[1];   // [64,1,512,512]
    const int*   labels      = (const int*)d_in[2];     // [64]
    const float* masks       = (const float*)d_in[3];   // [64,1,512,512]
    float* out = (float*)d_out;                          // [2]
    float* ws  = (float*)d_ws;

    // zero the completion counters every call (graph-legal memset node)
    hipMemsetAsync((char*)d_ws + CNT_BYTE_OFF, 0, CNT_CLEAR_SZ, stream);

    fused_kernel<<<GRID, TPB, 0, stream>>>(predict_seg, masks,
                                           predict_cls, labels, ws, out);
}

// Round 4
// 27.234 us; speedup vs baseline: 5.8949x; 5.8949x over previous
//
#include <hip/hip_runtime.h>

#define NSAMP 64
#define ELEMS (512 * 512)       // per-sample elements = 262144
#define NBLK  32                // blocks per sample
#define GRID  (NSAMP * NBLK)    // 2048 blocks = exactly 8/CU -> one resident round
#define TPB   256
#define PB    (ELEMS / NBLK)    // 8192 elements per block
#define N4    (PB / 4)          // 2048 float4 per block per array
#define BATCH 4                 // staged float4 per array per batch
#define NBATCH (N4 / (TPB * BATCH))   // 2 batches

__device__ __forceinline__ float sigmoid_fast(float x) {
    float e = __expf(-x);
    return __builtin_amdgcn_rcpf(1.0f + e);   // 1 ulp, fine at 2e-2 tolerance
}

// ---------------- Kernel 1: per-block partial reductions ----------------
// grid = 2048, block = 256. Each block reduces 8192 contiguous elements of
// one sample (32 KiB x 2 arrays): pg=sum(s*m), pp=sum(s*s), gg=sum(m),
// sm=sum(s), s=sigmoid(seg). One float4 partial per block.
__global__ __launch_bounds__(TPB) void partials_kernel(
    const float* __restrict__ seg, const float* __restrict__ msk,
    float* __restrict__ ws)
{
    const int b   = blockIdx.x >> 5;          // sample
    const int blk = blockIdx.x & (NBLK - 1);  // chunk within sample
    const size_t base = (size_t)b * ELEMS + (size_t)blk * PB;
    const float4* s4 = (const float4*)(seg + base);
    const float4* m4 = (const float4*)(msk + base);

    float pg = 0.f, pp = 0.f, gg = 0.f, sm = 0.f;

    for (int it = 0; it < NBATCH; ++it) {
        const int off = it * TPB * BATCH + threadIdx.x;
        float4 xs[BATCH], ms[BATCH];
        #pragma unroll
        for (int u = 0; u < BATCH; ++u) xs[u] = s4[off + u * TPB];
        #pragma unroll
        for (int u = 0; u < BATCH; ++u) ms[u] = m4[off + u * TPB];
        #pragma unroll
        for (int u = 0; u < BATCH; ++u) {
            float4 x = xs[u], m = ms[u];
            float s0 = sigmoid_fast(x.x);
            float s1 = sigmoid_fast(x.y);
            float s2 = sigmoid_fast(x.z);
            float s3 = sigmoid_fast(x.w);
            pg = fmaf(s0, m.x, pg); pg = fmaf(s1, m.y, pg);
            pg = fmaf(s2, m.z, pg); pg = fmaf(s3, m.w, pg);
            pp = fmaf(s0, s0, pp);  pp = fmaf(s1, s1, pp);
            pp = fmaf(s2, s2, pp);  pp = fmaf(s3, s3, pp);
            gg += (m.x + m.y) + (m.z + m.w);   // masks are 0/1 -> m*m == m
            sm += (s0 + s1) + (s2 + s3);
        }
    }

    // wave (64-lane) reduce
    #pragma unroll
    for (int o = 32; o; o >>= 1) {
        pg += __shfl_down(pg, o);
        pp += __shfl_down(pp, o);
        gg += __shfl_down(gg, o);
        sm += __shfl_down(sm, o);
    }

    // cross-wave reduce (4 waves)
    __shared__ float red[TPB / 64][4];
    const int lane = threadIdx.x & 63;
    const int wid  = threadIdx.x >> 6;
    if (lane == 0) {
        red[wid][0] = pg; red[wid][1] = pp;
        red[wid][2] = gg; red[wid][3] = sm;
    }
    __syncthreads();
    if (threadIdx.x == 0) {
        float a = red[0][0] + red[1][0] + red[2][0] + red[3][0];
        float c = red[0][1] + red[1][1] + red[2][1] + red[3][1];
        float d = red[0][2] + red[1][2] + red[2][2] + red[3][2];
        float e = red[0][3] + red[1][3] + red[2][3] + red[3][3];
        ((float4*)ws)[blockIdx.x] = make_float4(a, c, d, e);
    }
}

// ---------------- Kernel 2: finalize both losses ----------------
// One wave. Thread b handles sample b: sums its 32 float4 partials (float4
// loads, 512 B/thread), computes BCE term + dice, wave-reduces, writes out.
__global__ __launch_bounds__(64) void final_kernel(
    const float* __restrict__ pc, const int* __restrict__ labels,
    const float* __restrict__ ws, float* __restrict__ out)
{
    const int b = threadIdx.x;                 // 0..63 == sample
    const float4* w4 = (const float4*)ws + (size_t)b * NBLK;

    float pg = 0.f, pp = 0.f, gg = 0.f, sm = 0.f;
    #pragma unroll
    for (int i = 0; i < NBLK; ++i) {
        float4 v = w4[i];
        pg += v.x; pp += v.y; gg += v.z; sm += v.w;
    }

    float p   = pc[b];
    float lab = (float)labels[b];

    const float eps = 1e-7f;
    float pcc = fminf(fmaxf(p, eps), 1.f - eps);
    float bce = -(lab * logf(pcc) + (1.f - lab) * logf(1.f - pcc));

    float dice_pos = (2.f * pg + 1e-5f) / (pp + gg + 1e-5f);
    float dice_neg = 25.f / (sm + 25.f);
    float dice = (lab == 1.f) ? dice_pos : dice_neg;

    float sel  = (p >= 0.5f) ? 1.f : 0.f;
    float nsel = sel;
    float dsum = sel * dice;

    #pragma unroll
    for (int o = 32; o; o >>= 1) {
        bce  += __shfl_down(bce, o);
        nsel += __shfl_down(nsel, o);
        dsum += __shfl_down(dsum, o);
    }

    if (b == 0) {
        out[0] = bce * (1.0f / 64.0f);
        out[1] = (nsel > 0.f) ? (nsel - dsum) / fmaxf(nsel, 1.f) : 1e-4f;
    }
}

extern "C" void kernel_launch(void* const* d_in, const int* in_sizes, int n_in,
                              void* d_out, int out_size, void* d_ws, size_t ws_size,
                              hipStream_t stream) {
    const float* predict_cls = (const float*)d_in[0];   // [64]
    const float* predict_seg = (const float*)d_in[1];   // [64,1,512,512]
    const int*   labels      = (const int*)d_in[2];     // [64]
    const float* masks       = (const float*)d_in[3];   // [64,1,512,512]
    float* out = (float*)d_out;                          // [2]
    float* ws  = (float*)d_ws;                           // GRID float4 = 32 KiB

    partials_kernel<<<GRID, TPB, 0, stream>>>(predict_seg, masks, ws);
    final_kernel<<<1, 64, 0, stream>>>(predict_cls, labels, ws, out);
}